// Round 8
// baseline (980.365 us; speedup 1.0000x reference)
//
#include <hip/hip_runtime.h>
#include <hip/hip_bf16.h>

typedef __bf16 bf16_t;
typedef __bf16 bf16x8 __attribute__((ext_vector_type(8)));
typedef float f32x4 __attribute__((ext_vector_type(4)));

#define MFMA16(A, B, C) __builtin_amdgcn_mfma_f32_16x16x32_bf16(A, B, C, 0, 0, 0)

// Async global->LDS, 16B per lane. LDS dest is wave-uniform base + lane*16;
// global source is per-lane (pre-swizzle swizzled layouts on the source).
#define GLOAD_LDS16(gp, lp)                                           \
    __builtin_amdgcn_global_load_lds(                                 \
        (const __attribute__((address_space(1))) void*)(gp),          \
        (__attribute__((address_space(3))) void*)(lp), 16, 0, 0)

__device__ __forceinline__ uint32_t pack2(bf16_t a, bf16_t b) {
    union { bf16_t h[2]; uint32_t u; } x;
    x.h[0] = a; x.h[1] = b;
    return x.u;
}

// ---------------------------------------------------------------------------
// fp32 -> bf16 elementwise convert, 8 elems/thread, grid-stride.
// ---------------------------------------------------------------------------
__global__ __launch_bounds__(256)
void cvt_f32_bf16(const float* __restrict__ src, bf16_t* __restrict__ dst, int n8)
{
    int stride = gridDim.x * 256;
    for (int i = blockIdx.x * 256 + threadIdx.x; i < n8; i += stride) {
        const float4 f0 = *(const float4*)(src + (size_t)i * 8);
        const float4 f1 = *(const float4*)(src + (size_t)i * 8 + 4);
        bf16x8 v = {(bf16_t)f0.x, (bf16_t)f0.y, (bf16_t)f0.z, (bf16_t)f0.w,
                    (bf16_t)f1.x, (bf16_t)f1.y, (bf16_t)f1.z, (bf16_t)f1.w};
        *(bf16x8*)(dst + (size_t)i * 8) = v;
    }
}

// ---------------------------------------------------------------------------
// GEMM: C[M,N] = A[M,K] @ W[N,K]^T + bias[N]. A, W bf16; fp32 accum.
// m97 structure: 128x128 tile, BK=32, linear LDS, global_load_lds width=16.
// (XCD swizzle reverted: inputs are L3-resident -> wrong regime, measured
//  -45us in round 7.)
// ---------------------------------------------------------------------------
template <typename OT>
__global__ __launch_bounds__(256)
void gemm_bt_lds(const bf16_t* __restrict__ A, const bf16_t* __restrict__ W,
                 const float* __restrict__ bias, OT* __restrict__ C,
                 int M, int N, int K)
{
    __shared__ __align__(16) bf16_t lds_a[128 * 32];
    __shared__ __align__(16) bf16_t lds_b[128 * 32];

    const int tid  = threadIdx.x;
    const int wave = tid >> 6;
    const int lane = tid & 63;
    const int l15  = lane & 15;
    const int quad = lane >> 4;
    const int wm   = (wave >> 1) * 64;
    const int wn   = (wave & 1) * 64;

    const int bm = blockIdx.x * 128;
    const int bn = blockIdx.y * 128;

    const int srow = wave * 32 + (lane >> 2);
    const int scol = (lane & 3) * 8;

    const bf16_t* Ab = A + (size_t)(bm + srow) * K + scol;
    const bf16_t* Wb = W + (size_t)(bn + srow) * K + scol;
    bf16_t* la0 = &lds_a[wave * 32 * 32];
    bf16_t* lb0 = &lds_b[wave * 32 * 32];

    f32x4 acc[4][4] = {};

    for (int k0 = 0; k0 < K; k0 += 32) {
        GLOAD_LDS16(Ab + k0,          la0);
        GLOAD_LDS16(Ab + k0 + 16 * K, la0 + 16 * 32);
        GLOAD_LDS16(Wb + k0,          lb0);
        GLOAD_LDS16(Wb + k0 + 16 * K, lb0 + 16 * 32);
        __syncthreads();

        bf16x8 af[4], bfr[4];
        for (int i = 0; i < 4; ++i)
            af[i] = *(const bf16x8*)&lds_a[(wm + i * 16 + l15) * 32 + quad * 8];
        for (int j = 0; j < 4; ++j)
            bfr[j] = *(const bf16x8*)&lds_b[(wn + j * 16 + l15) * 32 + quad * 8];
        for (int i = 0; i < 4; ++i)
            for (int j = 0; j < 4; ++j)
                acc[i][j] = MFMA16(af[i], bfr[j], acc[i][j]);
        __syncthreads();
    }

    for (int i = 0; i < 4; ++i) {
        int mrow = bm + wm + i * 16 + quad * 4;
        for (int j = 0; j < 4; ++j) {
            int ncol = bn + wn + j * 16 + l15;
            float bval = bias[ncol];
            for (int r = 0; r < 4; ++r) {
                float v = acc[i][j][r] + bval;
                if constexpr (__is_same(OT, float))
                    C[(size_t)(mrow + r) * N + ncol] = v;
                else
                    C[(size_t)(mrow + r) * N + ncol] = (bf16_t)v;
            }
        }
    }
}

// ---------------------------------------------------------------------------
// RoPE in-place on Q and K (bf16 ws), layout [B*S, H*Dh], pairs (j, j+64).
// ---------------------------------------------------------------------------
__global__ __launch_bounds__(256)
void rope_kernel(bf16_t* __restrict__ Q, bf16_t* __restrict__ Kk)
{
    size_t idx = (size_t)blockIdx.x * 256 + threadIdx.x;
    int j = (int)(idx & 63);
    size_t rest = idx >> 6;
    int h = (int)(rest & 15);
    size_t row = rest >> 4;
    int s = (int)(row & 2047);

    float inv = __expf(-(float)j * 0.14391156831212787f);  // ln(10000)/64
    float ang = (float)s * inv;
    float sn, cs;
    sincosf(ang, &sn, &cs);

    size_t base = row * 2048 + (size_t)h * 128 + j;
    float q0 = (float)Q[base], q1 = (float)Q[base + 64];
    Q[base]      = (bf16_t)(q0 * cs - q1 * sn);
    Q[base + 64] = (bf16_t)(q1 * cs + q0 * sn);
    float k0 = (float)Kk[base], k1 = (float)Kk[base + 64];
    Kk[base]      = (bf16_t)(k0 * cs - k1 * sn);
    Kk[base + 64] = (bf16_t)(k1 * cs + k0 * sn);
}

// ---------------------------------------------------------------------------
// Transpose V [B,S,H*Dh] -> Vt [B,H,Dh,S]  (bf16)
// ---------------------------------------------------------------------------
__global__ __launch_bounds__(256)
void transpose_v(const bf16_t* __restrict__ V, bf16_t* __restrict__ Vt)
{
    __shared__ __align__(16) bf16_t tile[64][72];
    int bh = blockIdx.z;
    int b = bh >> 4, h = bh & 15;
    int t0 = blockIdx.x * 64;
    int d0 = blockIdx.y * 64;
    int tid = threadIdx.x;

    for (int i = 0; i < 2; ++i) {
        int c = tid + i * 256;
        int row = c >> 3, col = (c & 7) * 8;
        *(uint4*)&tile[row][col] =
            *(const uint4*)&V[((size_t)(b * 2048 + t0 + row)) * 2048 + h * 128 + d0 + col];
    }
    __syncthreads();
    for (int i = 0; i < 2; ++i) {
        int c = tid + i * 256;
        int drow = c >> 3, tcol = (c & 7) * 8;
        __align__(16) bf16_t tmp[8];
        for (int j = 0; j < 8; ++j) tmp[j] = tile[tcol + j][drow];
        *(uint4*)&Vt[((size_t)((b * 16 + h) * 128 + d0 + drow)) * 2048 + t0 + tcol] =
            *(uint4*)tmp;
    }
}

// ---------------------------------------------------------------------------
// Flash attention v5: v3's verified pipeline (gload_lds pre-swizzled K,
// double buffer, 1 barrier/tile, setprio, swapped QK^T / in-register
// softmax / swapped PV) with KVBLK 64->32: LDS drops 64KB -> 34KB so
// 4 blocks/CU (16 waves/CU) instead of 2 -- 2x latency hiding at identical
// per-element work. V rows are 64B: slot-class (l15&1)*4+quad is uniform
// -> no V swizzle needed; K keeps the verified (l15&7)<<4 swizzle.
// ---------------------------------------------------------------------------
__global__ __launch_bounds__(256, 4)
void flash_attn(const bf16_t* __restrict__ Q, const bf16_t* __restrict__ Kg,
                const bf16_t* __restrict__ Vt, bf16_t* __restrict__ Ctx)
{
    constexpr int S = 2048, H = 16, Dh = 128, D = 2048;
    constexpr int NT = S / 32;           // 64 tiles of 32 kv
    constexpr float scale = 0.08838834764831845f;  // 1/sqrt(128)

    // Double buffer: buf c at smem + c*16384 = [K 8KB | V 8KB].
    // Q prologue staging [128][136] (34816 B) owns the full smem.
    __shared__ __align__(16) char smem[34816];
    bf16_t* qst = (bf16_t*)smem;

    const int bh = blockIdx.y;
    const int b = bh >> 4, h = bh & 15;
    const int q0 = blockIdx.x * 128;
    const int tid = threadIdx.x, wave = tid >> 6, lane = tid & 63;
    const int l15 = lane & 15, quad = lane >> 4;
    const int hi2 = quad >> 1;
    const int swz = (l15 & 7) << 4;

    const bf16_t* Qh  = Q  + ((size_t)b * S) * D + h * Dh;
    const bf16_t* Kh  = Kg + ((size_t)b * S) * D + h * Dh;
    const bf16_t* Vth = Vt + ((size_t)(b * H + h)) * Dh * S;

    // Pre-swizzled per-lane source offsets (constant over kt).
    // K LDS linear [32 rows][256B]: 1KB issue = 4 rows; content slot is
    // XOR'd by row&7 (matches read-side swz since read row&7 = l15&7).
    // V LDS linear [128 rows][64B]: 1KB issue = 16 rows; linear (no swz).
    int ks_off[2], vs_off[2];
#pragma unroll
    for (int i = 0; i < 2; ++i) {
        int kr = i * 16 + wave * 4 + (lane >> 4);
        ks_off[i] = kr * D + (((lane & 15) ^ (kr & 7)) * 8);
        int vr = i * 64 + wave * 16 + (lane >> 2);
        vs_off[i] = vr * S + ((lane & 3) * 8);
    }

    // ---- prologue: stage Q tile [128 rows][128 cols], pull fragments.
    for (int i = 0; i < 8; ++i) {
        int c = tid + i * 256;
        int row = c >> 4, col = (c & 15) * 8;
        *(uint4*)&qst[row * 136 + col] =
            *(const uint4*)&Qh[(size_t)(q0 + row) * D + col];
    }
    __syncthreads();
    bf16x8 aq[2][4];   // B-operand frags: q rows wave*32 + g*16 + l15
    for (int g = 0; g < 2; ++g)
        for (int ks = 0; ks < 4; ++ks)
            aq[g][ks] = *(const bf16x8*)
                &qst[(wave * 32 + g * 16 + l15) * 136 + ks * 32 + quad * 8];
    __syncthreads();  // Q reads done before smem is reused for K/V

    float m_i[2] = {-3.0e4f, -3.0e4f};
    float l_i[2] = {0.f, 0.f};
    f32x4 ot[2][8] = {};   // O^T[d=16j+4quad+r][q=l15] per group

    // Stage tile 0 into buffer 0.
    {
        char* kb = smem;
        char* vb = smem + 8192;
#pragma unroll
        for (int i = 0; i < 2; ++i) {
            GLOAD_LDS16(Kh + ks_off[i],  kb + i * 4096 + wave * 1024);
            GLOAD_LDS16(Vth + vs_off[i], vb + i * 4096 + wave * 1024);
        }
    }
    __syncthreads();  // drains vmcnt -> buf0 ready

    for (int kt = 0; kt < NT; ++kt) {
        const int cur = kt & 1;
        // Issue next-tile staging first; latency hides under this tile's math.
        if (kt + 1 < NT) {
            char* kb = smem + (cur ^ 1) * 16384;
            char* vb = kb + 8192;
            const bf16_t* Ks = Kh + (size_t)(kt + 1) * 32 * D;
            const bf16_t* Vs = Vth + (kt + 1) * 32;
#pragma unroll
            for (int i = 0; i < 2; ++i) {
                GLOAD_LDS16(Ks + ks_off[i], kb + i * 4096 + wave * 1024);
                GLOAD_LDS16(Vs + vs_off[i], vb + i * 4096 + wave * 1024);
            }
        }
        const char* k_raw  = smem + cur * 16384;
        const char* vt_raw = k_raw + 8192;

        // QK^T swapped: st[g][kvs][r] = S[q=l15][kv = 16*kvs + 4*quad + r]
        f32x4 st[2][2] = {};
        __builtin_amdgcn_s_setprio(1);
        for (int ks = 0; ks < 4; ++ks)
            for (int kvs = 0; kvs < 2; ++kvs) {
                int row = kvs * 16 + l15;
                int off = (row * 256 + ks * 64 + quad * 16) ^ swz;
                bf16x8 kf = *(const bf16x8*)(k_raw + off);
                st[0][kvs] = MFMA16(kf, aq[0][ks], st[0][kvs]);
                st[1][kvs] = MFMA16(kf, aq[1][ks], st[1][kvs]);
            }
        __builtin_amdgcn_s_setprio(0);

        bf16x8 pb[2];
        for (int g = 0; g < 2; ++g) {
            // row-max over the 32-kv tile: 7 local fmax + 2 shfl_xor
            float pm = -3.0e4f;
            for (int kvs = 0; kvs < 2; ++kvs)
                for (int r = 0; r < 4; ++r) pm = fmaxf(pm, st[g][kvs][r]);
            pm = fmaxf(pm, __shfl_xor(pm, 16));
            pm = fmaxf(pm, __shfl_xor(pm, 32));
            pm *= scale;

            // defer-max (T13): skip O-rescale when max growth <= 8
            if (!__all(pm - m_i[g] <= 8.0f)) {
                float mnew  = fmaxf(m_i[g], pm);
                float alpha = __expf(m_i[g] - mnew);
                for (int j = 0; j < 8; ++j) ot[g][j] *= alpha;
                l_i[g] *= alpha;
                m_i[g] = mnew;
            }

            // P = exp(s*scale - m); quantize to bf16; sum quantized values
            uint32_t u[2][2];
            float ps = 0.f;
            for (int kvs = 0; kvs < 2; ++kvs) {
                bf16_t hq[4];
                for (int r = 0; r < 4; ++r) {
                    float pf = __expf(fmaf(st[g][kvs][r], scale, -m_i[g]));
                    hq[r] = (bf16_t)pf;
                    ps += (float)hq[r];
                }
                u[kvs][0] = pack2(hq[0], hq[1]);
                u[kvs][1] = pack2(hq[2], hq[3]);
            }
            ps += __shfl_xor(ps, 16);
            ps += __shfl_xor(ps, 32);
            l_i[g] += ps;

            // exchange D-layout P -> B-fragment layout:
            // need elem e of pb = P[l15][8*quad + e]; source kv = kvs*16+4q'+r
            int srcA = (quad & 1) * 32 + l15;
            int srcB = srcA + 16;
            uint32_t a00 = __shfl((int)u[0][0], srcA);
            uint32_t a01 = __shfl((int)u[0][1], srcA);
            uint32_t a10 = __shfl((int)u[1][0], srcA);
            uint32_t a11 = __shfl((int)u[1][1], srcA);
            uint32_t b00 = __shfl((int)u[0][0], srcB);
            uint32_t b01 = __shfl((int)u[0][1], srcB);
            uint32_t b10 = __shfl((int)u[1][0], srcB);
            uint32_t b11 = __shfl((int)u[1][1], srcB);
            union { uint32_t w[4]; bf16x8 v; } cc;
            cc.w[0] = hi2 ? a10 : a00;
            cc.w[1] = hi2 ? a11 : a01;
            cc.w[2] = hi2 ? b10 : b00;
            cc.w[3] = hi2 ? b11 : b01;
            pb[g] = cc.v;
        }

        // PV swapped: each Vt read feeds both groups (V rows 64B, linear)
        __builtin_amdgcn_s_setprio(1);
        for (int j = 0; j < 8; ++j) {
            int off = (j * 16 + l15) * 64 + quad * 16;
            bf16x8 av = *(const bf16x8*)(vt_raw + off);
            ot[0][j] = MFMA16(av, pb[0], ot[0][j]);
            ot[1][j] = MFMA16(av, pb[1], ot[1][j]);
        }
        __builtin_amdgcn_s_setprio(0);

        // One barrier per tile: (i) everyone done reading buf[cur] before
        // next iter's STAGE overwrites it; (ii) vmcnt drain means this
        // wave's gload_lds writes to buf[cur^1] have landed.
        __syncthreads();
    }

    // epilogue: 1/l is lane-local; regs r are contiguous d -> 8B stores
    for (int g = 0; g < 2; ++g) {
        float linv = 1.0f / l_i[g];
        size_t row = (size_t)b * S + q0 + wave * 32 + g * 16 + l15;
        for (int j = 0; j < 8; ++j) {
            union { bf16_t hh[4]; uint2 uu; } o;
            for (int r = 0; r < 4; ++r) o.hh[r] = (bf16_t)(ot[g][j][r] * linv);
            *(uint2*)&Ctx[row * D + h * Dh + j * 16 + quad * 4] = o.uu;
        }
    }
}

// ---------------------------------------------------------------------------
extern "C" void kernel_launch(void* const* d_in, const int* in_sizes, int n_in,
                              void* d_out, int out_size, void* d_ws, size_t ws_size,
                              hipStream_t stream)
{
    const float* x  = (const float*)d_in[0];
    const float* wq = (const float*)d_in[1];
    const float* bq = (const float*)d_in[2];
    const float* wk = (const float*)d_in[3];
    const float* bk = (const float*)d_in[4];
    const float* wv = (const float*)d_in[5];
    const float* bv = (const float*)d_in[6];
    const float* wo = (const float*)d_in[7];
    const float* bo = (const float*)d_in[8];
    float* out = (float*)d_out;

    const int B = 4, S = 2048, D = 2048, H = 16, Dh = 128;
    const int M = B * S;
    const size_t elems  = (size_t)M * D;   // 16,777,216
    const size_t welems = (size_t)D * D;   //  4,194,304

    // ws (bf16): Q | K | V(->Ctx) = 100.7 MiB.
    bf16_t* Qw  = (bf16_t*)d_ws;
    bf16_t* Kw  = Qw + elems;
    bf16_t* Vw  = Kw + elems;
    bf16_t* Ctx = Vw;
    bf16_t* wob = Qw;            // reuse Q region after flash_attn

    // d_out hosts transient bf16 data, dead before the final GEMM writes it.
    bf16_t* outb = (bf16_t*)d_out;
    bf16_t* xb   = outb;
    bf16_t* wqb  = outb + elems;
    bf16_t* wkb  = wqb + welems;
    bf16_t* wvb  = wkb + welems;
    bf16_t* Vtw  = outb;

    cvt_f32_bf16<<<2048, 256, 0, stream>>>(x,  xb,  (int)(elems / 8));
    cvt_f32_bf16<<<2048, 256, 0, stream>>>(wq, wqb, (int)(welems / 8));
    cvt_f32_bf16<<<2048, 256, 0, stream>>>(wk, wkb, (int)(welems / 8));
    cvt_f32_bf16<<<2048, 256, 0, stream>>>(wv, wvb, (int)(welems / 8));

    dim3 gGemm(M / 128, D / 128);
    gemm_bt_lds<bf16_t><<<gGemm, 256, 0, stream>>>(xb, wqb, bq, Qw, M, D, D);
    gemm_bt_lds<bf16_t><<<gGemm, 256, 0, stream>>>(xb, wkb, bk, Kw, M, D, D);
    gemm_bt_lds<bf16_t><<<gGemm, 256, 0, stream>>>(xb, wvb, bv, Vw, M, D, D);

    size_t nrope = (size_t)M * H * 64;
    rope_kernel<<<(int)(nrope / 256), 256, 0, stream>>>(Qw, Kw);

    dim3 gT(S / 64, Dh / 64, B * H);
    transpose_v<<<gT, 256, 0, stream>>>(Vw, Vtw);

    dim3 gA(S / 128, B * H);
    flash_attn<<<gA, 256, 0, stream>>>(Qw, Kw, Vtw, Ctx);

    cvt_f32_bf16<<<2048, 256, 0, stream>>>(wo, wob, (int)(welems / 8));
    gemm_bt_lds<float><<<gGemm, 256, 0, stream>>>(Ctx, wob, bo, out, M, D, D);
}

// Round 9
// 714.725 us; speedup vs baseline: 1.3717x; 1.3717x over previous
//
#include <hip/hip_runtime.h>
#include <hip/hip_bf16.h>

typedef __bf16 bf16_t;
typedef __bf16 bf16x8 __attribute__((ext_vector_type(8)));
typedef float f32x4 __attribute__((ext_vector_type(4)));

#define MFMA16(A, B, C) __builtin_amdgcn_mfma_f32_16x16x32_bf16(A, B, C, 0, 0, 0)

// Async global->LDS, 16B per lane. LDS dest is wave-uniform base + lane*16;
// global source is per-lane (pre-swizzle swizzled layouts on the source).
#define GLOAD_LDS16(gp, lp)                                           \
    __builtin_amdgcn_global_load_lds(                                 \
        (const __attribute__((address_space(1))) void*)(gp),          \
        (__attribute__((address_space(3))) void*)(lp), 16, 0, 0)

__device__ __forceinline__ uint32_t pack2(bf16_t a, bf16_t b) {
    union { bf16_t h[2]; uint32_t u; } x;
    x.h[0] = a; x.h[1] = b;
    return x.u;
}

// ---------------------------------------------------------------------------
// fp32 -> bf16 elementwise convert, 8 elems/thread, grid-stride.
// ---------------------------------------------------------------------------
__global__ __launch_bounds__(256)
void cvt_f32_bf16(const float* __restrict__ src, bf16_t* __restrict__ dst, int n8)
{
    int stride = gridDim.x * 256;
    for (int i = blockIdx.x * 256 + threadIdx.x; i < n8; i += stride) {
        const float4 f0 = *(const float4*)(src + (size_t)i * 8);
        const float4 f1 = *(const float4*)(src + (size_t)i * 8 + 4);
        bf16x8 v = {(bf16_t)f0.x, (bf16_t)f0.y, (bf16_t)f0.z, (bf16_t)f0.w,
                    (bf16_t)f1.x, (bf16_t)f1.y, (bf16_t)f1.z, (bf16_t)f1.w};
        *(bf16x8*)(dst + (size_t)i * 8) = v;
    }
}

// ---------------------------------------------------------------------------
// GEMM: C[M,N] = A[M,K] @ W[N,K]^T + bias[N]. A, W bf16; fp32 accum.
// m97 structure: 128x128 tile, BK=32, linear LDS, global_load_lds width=16.
// launch_bounds(256,3): cap VGPR ~170 to guarantee 3 waves/SIMD (m97's
// reference runs 164 VGPR at 874-912 TF; occupancy cliff at 2 waves costs
// ~30%, matching our inferred ~560 TF).
// ---------------------------------------------------------------------------
template <typename OT>
__global__ __launch_bounds__(256, 3)
void gemm_bt_lds(const bf16_t* __restrict__ A, const bf16_t* __restrict__ W,
                 const float* __restrict__ bias, OT* __restrict__ C,
                 int M, int N, int K)
{
    __shared__ __align__(16) bf16_t lds_a[128 * 32];
    __shared__ __align__(16) bf16_t lds_b[128 * 32];

    const int tid  = threadIdx.x;
    const int wave = tid >> 6;
    const int lane = tid & 63;
    const int l15  = lane & 15;
    const int quad = lane >> 4;
    const int wm   = (wave >> 1) * 64;
    const int wn   = (wave & 1) * 64;

    const int bm = blockIdx.x * 128;
    const int bn = blockIdx.y * 128;

    const int srow = wave * 32 + (lane >> 2);
    const int scol = (lane & 3) * 8;

    const bf16_t* Ab = A + (size_t)(bm + srow) * K + scol;
    const bf16_t* Wb = W + (size_t)(bn + srow) * K + scol;
    bf16_t* la0 = &lds_a[wave * 32 * 32];
    bf16_t* lb0 = &lds_b[wave * 32 * 32];

    f32x4 acc[4][4] = {};

    for (int k0 = 0; k0 < K; k0 += 32) {
        GLOAD_LDS16(Ab + k0,          la0);
        GLOAD_LDS16(Ab + k0 + 16 * K, la0 + 16 * 32);
        GLOAD_LDS16(Wb + k0,          lb0);
        GLOAD_LDS16(Wb + k0 + 16 * K, lb0 + 16 * 32);
        __syncthreads();

        bf16x8 af[4], bfr[4];
        for (int i = 0; i < 4; ++i)
            af[i] = *(const bf16x8*)&lds_a[(wm + i * 16 + l15) * 32 + quad * 8];
        for (int j = 0; j < 4; ++j)
            bfr[j] = *(const bf16x8*)&lds_b[(wn + j * 16 + l15) * 32 + quad * 8];
        for (int i = 0; i < 4; ++i)
            for (int j = 0; j < 4; ++j)
                acc[i][j] = MFMA16(af[i], bfr[j], acc[i][j]);
        __syncthreads();
    }

    for (int i = 0; i < 4; ++i) {
        int mrow = bm + wm + i * 16 + quad * 4;
        for (int j = 0; j < 4; ++j) {
            int ncol = bn + wn + j * 16 + l15;
            float bval = bias[ncol];
            for (int r = 0; r < 4; ++r) {
                float v = acc[i][j][r] + bval;
                if constexpr (__is_same(OT, float))
                    C[(size_t)(mrow + r) * N + ncol] = v;
                else
                    C[(size_t)(mrow + r) * N + ncol] = (bf16_t)v;
            }
        }
    }
}

// ---------------------------------------------------------------------------
// RoPE in-place on Q and K (bf16 ws), layout [B*S, H*Dh], pairs (j, j+64).
// ---------------------------------------------------------------------------
__global__ __launch_bounds__(256)
void rope_kernel(bf16_t* __restrict__ Q, bf16_t* __restrict__ Kk)
{
    size_t idx = (size_t)blockIdx.x * 256 + threadIdx.x;
    int j = (int)(idx & 63);
    size_t rest = idx >> 6;
    int h = (int)(rest & 15);
    size_t row = rest >> 4;
    int s = (int)(row & 2047);

    float inv = __expf(-(float)j * 0.14391156831212787f);  // ln(10000)/64
    float ang = (float)s * inv;
    float sn, cs;
    sincosf(ang, &sn, &cs);

    size_t base = row * 2048 + (size_t)h * 128 + j;
    float q0 = (float)Q[base], q1 = (float)Q[base + 64];
    Q[base]      = (bf16_t)(q0 * cs - q1 * sn);
    Q[base + 64] = (bf16_t)(q1 * cs + q0 * sn);
    float k0 = (float)Kk[base], k1 = (float)Kk[base + 64];
    Kk[base]      = (bf16_t)(k0 * cs - k1 * sn);
    Kk[base + 64] = (bf16_t)(k1 * cs + k0 * sn);
}

// ---------------------------------------------------------------------------
// Transpose V [B,S,H*Dh] -> Vt [B,H,Dh,S]  (bf16)
// ---------------------------------------------------------------------------
__global__ __launch_bounds__(256)
void transpose_v(const bf16_t* __restrict__ V, bf16_t* __restrict__ Vt)
{
    __shared__ __align__(16) bf16_t tile[64][72];
    int bh = blockIdx.z;
    int b = bh >> 4, h = bh & 15;
    int t0 = blockIdx.x * 64;
    int d0 = blockIdx.y * 64;
    int tid = threadIdx.x;

    for (int i = 0; i < 2; ++i) {
        int c = tid + i * 256;
        int row = c >> 3, col = (c & 7) * 8;
        *(uint4*)&tile[row][col] =
            *(const uint4*)&V[((size_t)(b * 2048 + t0 + row)) * 2048 + h * 128 + d0 + col];
    }
    __syncthreads();
    for (int i = 0; i < 2; ++i) {
        int c = tid + i * 256;
        int drow = c >> 3, tcol = (c & 7) * 8;
        __align__(16) bf16_t tmp[8];
        for (int j = 0; j < 8; ++j) tmp[j] = tile[tcol + j][drow];
        *(uint4*)&Vt[((size_t)((b * 16 + h) * 128 + d0 + drow)) * 2048 + t0 + tcol] =
            *(uint4*)tmp;
    }
}

// ---------------------------------------------------------------------------
// Flash attention v3 (harness-verified twice @224.9us): swapped QK^T /
// in-register softmax / swapped PV; K/V staged via global_load_lds with
// pre-swizzled per-lane global source; double-buffered (2x32KB); one
// barrier per tile; setprio around MFMA clusters; launch_bounds(256,2)
// -> 2 blocks/CU. NOTE (round 8 lesson): do NOT raise block residency --
// 4 blocks/CU breaks K/V L2 locality (FETCH 278MB -> 1.03GB, -75%).
// ---------------------------------------------------------------------------
__global__ __launch_bounds__(256, 2)
void flash_attn(const bf16_t* __restrict__ Q, const bf16_t* __restrict__ Kg,
                const bf16_t* __restrict__ Vt, bf16_t* __restrict__ Ctx)
{
    constexpr int S = 2048, H = 16, Dh = 128, D = 2048;
    constexpr int NT = S / 64;
    constexpr float scale = 0.08838834764831845f;  // 1/sqrt(128)

    // Double buffer: buf c at smem + c*32768 = [K 16KB | Vt 16KB].
    // Q prologue staging [128][136] (34816 B) aliases the front of smem.
    __shared__ __align__(16) char smem[65536];
    bf16_t* qst = (bf16_t*)smem;

    const int bh = blockIdx.y;
    const int b = bh >> 4, h = bh & 15;
    const int q0 = blockIdx.x * 128;
    const int tid = threadIdx.x, wave = tid >> 6, lane = tid & 63;
    const int l15 = lane & 15, quad = lane >> 4;
    const int hi2 = quad >> 1;
    const int swz = (l15 & 7) << 4;

    const bf16_t* Qh  = Q  + ((size_t)b * S) * D + h * Dh;
    const bf16_t* Kh  = Kg + ((size_t)b * S) * D + h * Dh;
    const bf16_t* Vth = Vt + ((size_t)(b * H + h)) * Dh * S;

    // Pre-swizzled per-lane source offsets (constant over kt).
    int ks_off[4], vs_off[4];
#pragma unroll
    for (int i = 0; i < 4; ++i) {
        int kr = wave * 16 + i * 4 + (lane >> 4);
        int ksl = lane & 15;
        ks_off[i] = kr * D + ((ksl ^ (kr & 7)) * 8);
        int vr = wave * 32 + i * 8 + (lane >> 3);
        int vsl = lane & 7;
        vs_off[i] = vr * S + ((vsl ^ (vr & 7)) * 8);
    }

    // ---- prologue: stage Q tile [128 rows][128 cols], pull fragments.
    for (int i = 0; i < 8; ++i) {
        int c = tid + i * 256;
        int row = c >> 4, col = (c & 15) * 8;
        *(uint4*)&qst[row * 136 + col] =
            *(const uint4*)&Qh[(size_t)(q0 + row) * D + col];
    }
    __syncthreads();
    bf16x8 aq[2][4];   // B-operand frags: q rows wave*32 + g*16 + l15
    for (int g = 0; g < 2; ++g)
        for (int ks = 0; ks < 4; ++ks)
            aq[g][ks] = *(const bf16x8*)
                &qst[(wave * 32 + g * 16 + l15) * 136 + ks * 32 + quad * 8];
    __syncthreads();  // Q reads done before smem is reused for K/V

    float m_i[2] = {-3.0e4f, -3.0e4f};
    float l_i[2] = {0.f, 0.f};
    f32x4 ot[2][8] = {};   // O^T[d=16j+4quad+r][q=l15] per group

    // Stage tile 0 into buffer 0.
    {
        char* kb = smem;
        char* vb = smem + 16384;
        const bf16_t* Vs = Vth;
#pragma unroll
        for (int i = 0; i < 4; ++i) {
            GLOAD_LDS16(Kh + ks_off[i], kb + wave * 4096 + i * 1024);
            GLOAD_LDS16(Vs + vs_off[i], vb + wave * 4096 + i * 1024);
        }
    }
    __syncthreads();  // drains vmcnt -> buf0 ready

    for (int kt = 0; kt < NT; ++kt) {
        const int cur = kt & 1;
        // Issue next-tile staging first; latency hides under this tile's math.
        if (kt + 1 < NT) {
            char* kb = smem + (cur ^ 1) * 32768;
            char* vb = kb + 16384;
            const bf16_t* Ks = Kh + (size_t)(kt + 1) * 64 * D;
            const bf16_t* Vs = Vth + (kt + 1) * 64;
#pragma unroll
            for (int i = 0; i < 4; ++i) {
                GLOAD_LDS16(Ks + ks_off[i], kb + wave * 4096 + i * 1024);
                GLOAD_LDS16(Vs + vs_off[i], vb + wave * 4096 + i * 1024);
            }
        }
        const char* k_raw  = smem + cur * 32768;
        const char* vt_raw = k_raw + 16384;

        // QK^T swapped: st[g][kvs][r] = S[q=l15][kv = 16*kvs + 4*quad + r]
        f32x4 st[2][4] = {};
        __builtin_amdgcn_s_setprio(1);
        for (int ks = 0; ks < 4; ++ks)
            for (int kvs = 0; kvs < 4; ++kvs) {
                int row = kvs * 16 + l15;
                int off = (row * 256 + ks * 64 + quad * 16) ^ swz;
                bf16x8 kf = *(const bf16x8*)(k_raw + off);
                st[0][kvs] = MFMA16(kf, aq[0][ks], st[0][kvs]);
                st[1][kvs] = MFMA16(kf, aq[1][ks], st[1][kvs]);
            }
        __builtin_amdgcn_s_setprio(0);

        bf16x8 pb[2][2];
        for (int g = 0; g < 2; ++g) {
            // row-max over the 64-kv tile: 15 local fmax + 2 shfl_xor
            float pm = -3.0e4f;
            for (int kvs = 0; kvs < 4; ++kvs)
                for (int r = 0; r < 4; ++r) pm = fmaxf(pm, st[g][kvs][r]);
            pm = fmaxf(pm, __shfl_xor(pm, 16));
            pm = fmaxf(pm, __shfl_xor(pm, 32));
            pm *= scale;

            // defer-max (T13): skip O-rescale when max growth <= 8
            if (!__all(pm - m_i[g] <= 8.0f)) {
                float mnew  = fmaxf(m_i[g], pm);
                float alpha = __expf(m_i[g] - mnew);
                for (int j = 0; j < 8; ++j) ot[g][j] *= alpha;
                l_i[g] *= alpha;
                m_i[g] = mnew;
            }

            // P = exp(s*scale - m); quantize to bf16; sum quantized values
            uint32_t u[4][2];
            float ps = 0.f;
            for (int kvs = 0; kvs < 4; ++kvs) {
                bf16_t hq[4];
                for (int r = 0; r < 4; ++r) {
                    float pf = __expf(fmaf(st[g][kvs][r], scale, -m_i[g]));
                    hq[r] = (bf16_t)pf;
                    ps += (float)hq[r];
                }
                u[kvs][0] = pack2(hq[0], hq[1]);
                u[kvs][1] = pack2(hq[2], hq[3]);
            }
            ps += __shfl_xor(ps, 16);
            ps += __shfl_xor(ps, 32);
            l_i[g] += ps;

            // exchange D-layout P -> B-fragment layout:
            // need elem e of pb[kk] = P[l15][32kk + 8quad + e]
            int srcA = (quad & 1) * 32 + l15;
            int srcB = srcA + 16;
            for (int kk = 0; kk < 2; ++kk) {
                uint32_t a00 = __shfl((int)u[2 * kk + 0][0], srcA);
                uint32_t a01 = __shfl((int)u[2 * kk + 0][1], srcA);
                uint32_t a10 = __shfl((int)u[2 * kk + 1][0], srcA);
                uint32_t a11 = __shfl((int)u[2 * kk + 1][1], srcA);
                uint32_t b00 = __shfl((int)u[2 * kk + 0][0], srcB);
                uint32_t b01 = __shfl((int)u[2 * kk + 0][1], srcB);
                uint32_t b10 = __shfl((int)u[2 * kk + 1][0], srcB);
                uint32_t b11 = __shfl((int)u[2 * kk + 1][1], srcB);
                union { uint32_t w[4]; bf16x8 v; } cc;
                cc.w[0] = hi2 ? a10 : a00;
                cc.w[1] = hi2 ? a11 : a01;
                cc.w[2] = hi2 ? b10 : b00;
                cc.w[3] = hi2 ? b11 : b01;
                pb[g][kk] = cc.v;
            }
        }

        // PV swapped: each Vt read feeds both groups
        __builtin_amdgcn_s_setprio(1);
        for (int j = 0; j < 8; ++j)
            for (int kk = 0; kk < 2; ++kk) {
                int row = j * 16 + l15;
                int off = (row * 128 + kk * 64 + quad * 16) ^ swz;
                bf16x8 av = *(const bf16x8*)(vt_raw + off);
                ot[0][j] = MFMA16(av, pb[0][kk], ot[0][j]);
                ot[1][j] = MFMA16(av, pb[1][kk], ot[1][j]);
            }
        __builtin_amdgcn_s_setprio(0);

        // One barrier per tile.
        __syncthreads();
    }

    // epilogue: 1/l is lane-local; regs r are contiguous d -> 8B stores
    for (int g = 0; g < 2; ++g) {
        float linv = 1.0f / l_i[g];
        size_t row = (size_t)b * S + q0 + wave * 32 + g * 16 + l15;
        for (int j = 0; j < 8; ++j) {
            union { bf16_t hh[4]; uint2 uu; } o;
            for (int r = 0; r < 4; ++r) o.hh[r] = (bf16_t)(ot[g][j][r] * linv);
            *(uint2*)&Ctx[row * D + h * Dh + j * 16 + quad * 4] = o.uu;
        }
    }
}

// ---------------------------------------------------------------------------
extern "C" void kernel_launch(void* const* d_in, const int* in_sizes, int n_in,
                              void* d_out, int out_size, void* d_ws, size_t ws_size,
                              hipStream_t stream)
{
    const float* x  = (const float*)d_in[0];
    const float* wq = (const float*)d_in[1];
    const float* bq = (const float*)d_in[2];
    const float* wk = (const float*)d_in[3];
    const float* bk = (const float*)d_in[4];
    const float* wv = (const float*)d_in[5];
    const float* bv = (const float*)d_in[6];
    const float* wo = (const float*)d_in[7];
    const float* bo = (const float*)d_in[8];
    float* out = (float*)d_out;

    const int B = 4, S = 2048, D = 2048, H = 16, Dh = 128;
    const int M = B * S;
    const size_t elems  = (size_t)M * D;   // 16,777,216
    const size_t welems = (size_t)D * D;   //  4,194,304

    // ws (bf16): Q | K | V(->Ctx) = 100.7 MiB.
    bf16_t* Qw  = (bf16_t*)d_ws;
    bf16_t* Kw  = Qw + elems;
    bf16_t* Vw  = Kw + elems;
    bf16_t* Ctx = Vw;
    bf16_t* wob = Qw;            // reuse Q region after flash_attn

    // d_out hosts transient bf16 data, dead before the final GEMM writes it.
    bf16_t* outb = (bf16_t*)d_out;
    bf16_t* xb   = outb;
    bf16_t* wqb  = outb + elems;
    bf16_t* wkb  = wqb + welems;
    bf16_t* wvb  = wkb + welems;
    bf16_t* Vtw  = outb;

    cvt_f32_bf16<<<2048, 256, 0, stream>>>(x,  xb,  (int)(elems / 8));
    cvt_f32_bf16<<<2048, 256, 0, stream>>>(wq, wqb, (int)(welems / 8));
    cvt_f32_bf16<<<2048, 256, 0, stream>>>(wk, wkb, (int)(welems / 8));
    cvt_f32_bf16<<<2048, 256, 0, stream>>>(wv, wvb, (int)(welems / 8));

    dim3 gGemm(M / 128, D / 128);
    gemm_bt_lds<bf16_t><<<gGemm, 256, 0, stream>>>(xb, wqb, bq, Qw, M, D, D);
    gemm_bt_lds<bf16_t><<<gGemm, 256, 0, stream>>>(xb, wkb, bk, Kw, M, D, D);
    gemm_bt_lds<bf16_t><<<gGemm, 256, 0, stream>>>(xb, wvb, bv, Vw, M, D, D);

    size_t nrope = (size_t)M * H * 64;
    rope_kernel<<<(int)(nrope / 256), 256, 0, stream>>>(Qw, Kw);

    dim3 gT(S / 64, Dh / 64, B * H);
    transpose_v<<<gT, 256, 0, stream>>>(Vw, Vtw);

    dim3 gA(S / 128, B * H);
    flash_attn<<<gA, 256, 0, stream>>>(Qw, Kw, Vtw, Ctx);

    cvt_f32_bf16<<<2048, 256, 0, stream>>>(wo, wob, (int)(welems / 8));
    gemm_bt_lds<float><<<gGemm, 256, 0, stream>>>(Ctx, wob, bo, out, M, D, D);
}

// Round 10
// 686.987 us; speedup vs baseline: 1.4271x; 1.0404x over previous
//
#include <hip/hip_runtime.h>
#include <hip/hip_bf16.h>

typedef __bf16 bf16_t;
typedef __bf16 bf16x8 __attribute__((ext_vector_type(8)));
typedef float f32x4 __attribute__((ext_vector_type(4)));

#define MFMA16(A, B, C) __builtin_amdgcn_mfma_f32_16x16x32_bf16(A, B, C, 0, 0, 0)

// Async global->LDS, 16B per lane. LDS dest is wave-uniform base + lane*16;
// global source is per-lane (pre-swizzle swizzled layouts on the source).
#define GLOAD_LDS16(gp, lp)                                           \
    __builtin_amdgcn_global_load_lds(                                 \
        (const __attribute__((address_space(1))) void*)(gp),          \
        (__attribute__((address_space(3))) void*)(lp), 16, 0, 0)

__device__ __forceinline__ uint32_t pack2(bf16_t a, bf16_t b) {
    union { bf16_t h[2]; uint32_t u; } x;
    x.h[0] = a; x.h[1] = b;
    return x.u;
}

// ---------------------------------------------------------------------------
// fp32 -> bf16 elementwise convert, 8 elems/thread, grid-stride.
// ---------------------------------------------------------------------------
__global__ __launch_bounds__(256)
void cvt_f32_bf16(const float* __restrict__ src, bf16_t* __restrict__ dst, int n8)
{
    int stride = gridDim.x * 256;
    for (int i = blockIdx.x * 256 + threadIdx.x; i < n8; i += stride) {
        const float4 f0 = *(const float4*)(src + (size_t)i * 8);
        const float4 f1 = *(const float4*)(src + (size_t)i * 8 + 4);
        bf16x8 v = {(bf16_t)f0.x, (bf16_t)f0.y, (bf16_t)f0.z, (bf16_t)f0.w,
                    (bf16_t)f1.x, (bf16_t)f1.y, (bf16_t)f1.z, (bf16_t)f1.w};
        *(bf16x8*)(dst + (size_t)i * 8) = v;
    }
}

// ---------------------------------------------------------------------------
// Merged QKV GEMM: [Q|K|V] = x @ [wq|wk|wv]^T + b.  Wqkv is the stacked
// [6144, 2048] bf16 weight (wqb/wkb/wvb staged contiguously). Grid 64x48 =
// 3072 blocks = exactly 4 full 768-block waves at 3 blocks/CU -- removes
// the 1/3-full tail batch paid 3x by separate launches. Epilogue routes by
// matrix id (bn>>11, wave-uniform) so downstream kernels are unchanged.
// Core loop identical to gemm_bt_lds (m97 structure, verified).
// ---------------------------------------------------------------------------
__global__ __launch_bounds__(256, 3)
void gemm_qkv(const bf16_t* __restrict__ A, const bf16_t* __restrict__ Wqkv,
              const float* __restrict__ bq, const float* __restrict__ bk,
              const float* __restrict__ bv, bf16_t* __restrict__ Qo,
              bf16_t* __restrict__ Ko, bf16_t* __restrict__ Vo,
              int M, int K)
{
    __shared__ __align__(16) bf16_t lds_a[128 * 32];
    __shared__ __align__(16) bf16_t lds_b[128 * 32];

    const int tid  = threadIdx.x;
    const int wave = tid >> 6;
    const int lane = tid & 63;
    const int l15  = lane & 15;
    const int quad = lane >> 4;
    const int wm   = (wave >> 1) * 64;
    const int wn   = (wave & 1) * 64;

    const int bm      = blockIdx.x * 128;
    const int bn_full = blockIdx.y * 128;          // [0, 6144)
    const int mid     = bn_full >> 11;             // 0=Q 1=K 2=V
    const int bn      = bn_full & 2047;            // col within matrix

    const float* bias = (mid == 0) ? bq : (mid == 1) ? bk : bv;
    bf16_t*      Cm   = (mid == 0) ? Qo : (mid == 1) ? Ko : Vo;

    const int srow = wave * 32 + (lane >> 2);
    const int scol = (lane & 3) * 8;

    const bf16_t* Ab = A    + (size_t)(bm + srow) * K + scol;
    const bf16_t* Wb = Wqkv + (size_t)(bn_full + srow) * K + scol;
    bf16_t* la0 = &lds_a[wave * 32 * 32];
    bf16_t* lb0 = &lds_b[wave * 32 * 32];

    f32x4 acc[4][4] = {};

    for (int k0 = 0; k0 < K; k0 += 32) {
        GLOAD_LDS16(Ab + k0,          la0);
        GLOAD_LDS16(Ab + k0 + 16 * K, la0 + 16 * 32);
        GLOAD_LDS16(Wb + k0,          lb0);
        GLOAD_LDS16(Wb + k0 + 16 * K, lb0 + 16 * 32);
        __syncthreads();

        bf16x8 af[4], bfr[4];
        for (int i = 0; i < 4; ++i)
            af[i] = *(const bf16x8*)&lds_a[(wm + i * 16 + l15) * 32 + quad * 8];
        for (int j = 0; j < 4; ++j)
            bfr[j] = *(const bf16x8*)&lds_b[(wn + j * 16 + l15) * 32 + quad * 8];
        for (int i = 0; i < 4; ++i)
            for (int j = 0; j < 4; ++j)
                acc[i][j] = MFMA16(af[i], bfr[j], acc[i][j]);
        __syncthreads();
    }

    for (int i = 0; i < 4; ++i) {
        int mrow = bm + wm + i * 16 + quad * 4;
        for (int j = 0; j < 4; ++j) {
            int ncol = bn + wn + j * 16 + l15;
            float bval = bias[ncol];
            for (int r = 0; r < 4; ++r) {
                float v = acc[i][j][r] + bval;
                Cm[(size_t)(mrow + r) * 2048 + ncol] = (bf16_t)v;
            }
        }
    }
}

// ---------------------------------------------------------------------------
// GEMM: C[M,N] = A[M,K] @ W[N,K]^T + bias[N]. A, W bf16; fp32 accum.
// m97 structure: 128x128 tile, BK=32, linear LDS, global_load_lds width=16.
// launch_bounds(256,3): cap VGPR ~170 for 3 waves/SIMD (round 9: -77us).
// ---------------------------------------------------------------------------
template <typename OT>
__global__ __launch_bounds__(256, 3)
void gemm_bt_lds(const bf16_t* __restrict__ A, const bf16_t* __restrict__ W,
                 const float* __restrict__ bias, OT* __restrict__ C,
                 int M, int N, int K)
{
    __shared__ __align__(16) bf16_t lds_a[128 * 32];
    __shared__ __align__(16) bf16_t lds_b[128 * 32];

    const int tid  = threadIdx.x;
    const int wave = tid >> 6;
    const int lane = tid & 63;
    const int l15  = lane & 15;
    const int quad = lane >> 4;
    const int wm   = (wave >> 1) * 64;
    const int wn   = (wave & 1) * 64;

    const int bm = blockIdx.x * 128;
    const int bn = blockIdx.y * 128;

    const int srow = wave * 32 + (lane >> 2);
    const int scol = (lane & 3) * 8;

    const bf16_t* Ab = A + (size_t)(bm + srow) * K + scol;
    const bf16_t* Wb = W + (size_t)(bn + srow) * K + scol;
    bf16_t* la0 = &lds_a[wave * 32 * 32];
    bf16_t* lb0 = &lds_b[wave * 32 * 32];

    f32x4 acc[4][4] = {};

    for (int k0 = 0; k0 < K; k0 += 32) {
        GLOAD_LDS16(Ab + k0,          la0);
        GLOAD_LDS16(Ab + k0 + 16 * K, la0 + 16 * 32);
        GLOAD_LDS16(Wb + k0,          lb0);
        GLOAD_LDS16(Wb + k0 + 16 * K, lb0 + 16 * 32);
        __syncthreads();

        bf16x8 af[4], bfr[4];
        for (int i = 0; i < 4; ++i)
            af[i] = *(const bf16x8*)&lds_a[(wm + i * 16 + l15) * 32 + quad * 8];
        for (int j = 0; j < 4; ++j)
            bfr[j] = *(const bf16x8*)&lds_b[(wn + j * 16 + l15) * 32 + quad * 8];
        for (int i = 0; i < 4; ++i)
            for (int j = 0; j < 4; ++j)
                acc[i][j] = MFMA16(af[i], bfr[j], acc[i][j]);
        __syncthreads();
    }

    for (int i = 0; i < 4; ++i) {
        int mrow = bm + wm + i * 16 + quad * 4;
        for (int j = 0; j < 4; ++j) {
            int ncol = bn + wn + j * 16 + l15;
            float bval = bias[ncol];
            for (int r = 0; r < 4; ++r) {
                float v = acc[i][j][r] + bval;
                if constexpr (__is_same(OT, float))
                    C[(size_t)(mrow + r) * N + ncol] = v;
                else
                    C[(size_t)(mrow + r) * N + ncol] = (bf16_t)v;
            }
        }
    }
}

// ---------------------------------------------------------------------------
// RoPE in-place on Q and K (bf16 ws), layout [B*S, H*Dh], pairs (j, j+64).
// ---------------------------------------------------------------------------
__global__ __launch_bounds__(256)
void rope_kernel(bf16_t* __restrict__ Q, bf16_t* __restrict__ Kk)
{
    size_t idx = (size_t)blockIdx.x * 256 + threadIdx.x;
    int j = (int)(idx & 63);
    size_t rest = idx >> 6;
    int h = (int)(rest & 15);
    size_t row = rest >> 4;
    int s = (int)(row & 2047);

    float inv = __expf(-(float)j * 0.14391156831212787f);  // ln(10000)/64
    float ang = (float)s * inv;
    float sn, cs;
    sincosf(ang, &sn, &cs);

    size_t base = row * 2048 + (size_t)h * 128 + j;
    float q0 = (float)Q[base], q1 = (float)Q[base + 64];
    Q[base]      = (bf16_t)(q0 * cs - q1 * sn);
    Q[base + 64] = (bf16_t)(q1 * cs + q0 * sn);
    float k0 = (float)Kk[base], k1 = (float)Kk[base + 64];
    Kk[base]      = (bf16_t)(k0 * cs - k1 * sn);
    Kk[base + 64] = (bf16_t)(k1 * cs + k0 * sn);
}

// ---------------------------------------------------------------------------
// Transpose V [B,S,H*Dh] -> Vt [B,H,Dh,S]  (bf16)
// ---------------------------------------------------------------------------
__global__ __launch_bounds__(256)
void transpose_v(const bf16_t* __restrict__ V, bf16_t* __restrict__ Vt)
{
    __shared__ __align__(16) bf16_t tile[64][72];
    int bh = blockIdx.z;
    int b = bh >> 4, h = bh & 15;
    int t0 = blockIdx.x * 64;
    int d0 = blockIdx.y * 64;
    int tid = threadIdx.x;

    for (int i = 0; i < 2; ++i) {
        int c = tid + i * 256;
        int row = c >> 3, col = (c & 7) * 8;
        *(uint4*)&tile[row][col] =
            *(const uint4*)&V[((size_t)(b * 2048 + t0 + row)) * 2048 + h * 128 + d0 + col];
    }
    __syncthreads();
    for (int i = 0; i < 2; ++i) {
        int c = tid + i * 256;
        int drow = c >> 3, tcol = (c & 7) * 8;
        __align__(16) bf16_t tmp[8];
        for (int j = 0; j < 8; ++j) tmp[j] = tile[tcol + j][drow];
        *(uint4*)&Vt[((size_t)((b * 16 + h) * 128 + d0 + drow)) * 2048 + t0 + tcol] =
            *(uint4*)tmp;
    }
}

// ---------------------------------------------------------------------------
// Flash attention v3 (harness-verified 3x @224.9us): swapped QK^T /
// in-register softmax / swapped PV; K/V staged via global_load_lds with
// pre-swizzled per-lane global source; double-buffered (2x32KB); one
// barrier per tile; setprio around MFMA clusters; launch_bounds(256,2)
// -> 2 blocks/CU. NOTE (round 8 lesson): do NOT raise block residency --
// 4 blocks/CU breaks K/V L2 locality (FETCH 278MB -> 1.03GB, -75%).
// ---------------------------------------------------------------------------
__global__ __launch_bounds__(256, 2)
void flash_attn(const bf16_t* __restrict__ Q, const bf16_t* __restrict__ Kg,
                const bf16_t* __restrict__ Vt, bf16_t* __restrict__ Ctx)
{
    constexpr int S = 2048, H = 16, Dh = 128, D = 2048;
    constexpr int NT = S / 64;
    constexpr float scale = 0.08838834764831845f;  // 1/sqrt(128)

    // Double buffer: buf c at smem + c*32768 = [K 16KB | Vt 16KB].
    // Q prologue staging [128][136] (34816 B) aliases the front of smem.
    __shared__ __align__(16) char smem[65536];
    bf16_t* qst = (bf16_t*)smem;

    const int bh = blockIdx.y;
    const int b = bh >> 4, h = bh & 15;
    const int q0 = blockIdx.x * 128;
    const int tid = threadIdx.x, wave = tid >> 6, lane = tid & 63;
    const int l15 = lane & 15, quad = lane >> 4;
    const int hi2 = quad >> 1;
    const int swz = (l15 & 7) << 4;

    const bf16_t* Qh  = Q  + ((size_t)b * S) * D + h * Dh;
    const bf16_t* Kh  = Kg + ((size_t)b * S) * D + h * Dh;
    const bf16_t* Vth = Vt + ((size_t)(b * H + h)) * Dh * S;

    // Pre-swizzled per-lane source offsets (constant over kt).
    int ks_off[4], vs_off[4];
#pragma unroll
    for (int i = 0; i < 4; ++i) {
        int kr = wave * 16 + i * 4 + (lane >> 4);
        int ksl = lane & 15;
        ks_off[i] = kr * D + ((ksl ^ (kr & 7)) * 8);
        int vr = wave * 32 + i * 8 + (lane >> 3);
        int vsl = lane & 7;
        vs_off[i] = vr * S + ((vsl ^ (vr & 7)) * 8);
    }

    // ---- prologue: stage Q tile [128 rows][128 cols], pull fragments.
    for (int i = 0; i < 8; ++i) {
        int c = tid + i * 256;
        int row = c >> 4, col = (c & 15) * 8;
        *(uint4*)&qst[row * 136 + col] =
            *(const uint4*)&Qh[(size_t)(q0 + row) * D + col];
    }
    __syncthreads();
    bf16x8 aq[2][4];   // B-operand frags: q rows wave*32 + g*16 + l15
    for (int g = 0; g < 2; ++g)
        for (int ks = 0; ks < 4; ++ks)
            aq[g][ks] = *(const bf16x8*)
                &qst[(wave * 32 + g * 16 + l15) * 136 + ks * 32 + quad * 8];
    __syncthreads();  // Q reads done before smem is reused for K/V

    float m_i[2] = {-3.0e4f, -3.0e4f};
    float l_i[2] = {0.f, 0.f};
    f32x4 ot[2][8] = {};   // O^T[d=16j+4quad+r][q=l15] per group

    // Stage tile 0 into buffer 0.
    {
        char* kb = smem;
        char* vb = smem + 16384;
        const bf16_t* Vs = Vth;
#pragma unroll
        for (int i = 0; i < 4; ++i) {
            GLOAD_LDS16(Kh + ks_off[i], kb + wave * 4096 + i * 1024);
            GLOAD_LDS16(Vs + vs_off[i], vb + wave * 4096 + i * 1024);
        }
    }
    __syncthreads();  // drains vmcnt -> buf0 ready

    for (int kt = 0; kt < NT; ++kt) {
        const int cur = kt & 1;
        // Issue next-tile staging first; latency hides under this tile's math.
        if (kt + 1 < NT) {
            char* kb = smem + (cur ^ 1) * 32768;
            char* vb = kb + 16384;
            const bf16_t* Ks = Kh + (size_t)(kt + 1) * 64 * D;
            const bf16_t* Vs = Vth + (kt + 1) * 64;
#pragma unroll
            for (int i = 0; i < 4; ++i) {
                GLOAD_LDS16(Ks + ks_off[i], kb + wave * 4096 + i * 1024);
                GLOAD_LDS16(Vs + vs_off[i], vb + wave * 4096 + i * 1024);
            }
        }
        const char* k_raw  = smem + cur * 32768;
        const char* vt_raw = k_raw + 16384;

        // QK^T swapped: st[g][kvs][r] = S[q=l15][kv = 16*kvs + 4*quad + r]
        f32x4 st[2][4] = {};
        __builtin_amdgcn_s_setprio(1);
        for (int ks = 0; ks < 4; ++ks)
            for (int kvs = 0; kvs < 4; ++kvs) {
                int row = kvs * 16 + l15;
                int off = (row * 256 + ks * 64 + quad * 16) ^ swz;
                bf16x8 kf = *(const bf16x8*)(k_raw + off);
                st[0][kvs] = MFMA16(kf, aq[0][ks], st[0][kvs]);
                st[1][kvs] = MFMA16(kf, aq[1][ks], st[1][kvs]);
            }
        __builtin_amdgcn_s_setprio(0);

        bf16x8 pb[2][2];
        for (int g = 0; g < 2; ++g) {
            // row-max over the 64-kv tile: 15 local fmax + 2 shfl_xor
            float pm = -3.0e4f;
            for (int kvs = 0; kvs < 4; ++kvs)
                for (int r = 0; r < 4; ++r) pm = fmaxf(pm, st[g][kvs][r]);
            pm = fmaxf(pm, __shfl_xor(pm, 16));
            pm = fmaxf(pm, __shfl_xor(pm, 32));
            pm *= scale;

            // defer-max (T13): skip O-rescale when max growth <= 8
            if (!__all(pm - m_i[g] <= 8.0f)) {
                float mnew  = fmaxf(m_i[g], pm);
                float alpha = __expf(m_i[g] - mnew);
                for (int j = 0; j < 8; ++j) ot[g][j] *= alpha;
                l_i[g] *= alpha;
                m_i[g] = mnew;
            }

            // P = exp(s*scale - m); quantize to bf16; sum quantized values
            uint32_t u[4][2];
            float ps = 0.f;
            for (int kvs = 0; kvs < 4; ++kvs) {
                bf16_t hq[4];
                for (int r = 0; r < 4; ++r) {
                    float pf = __expf(fmaf(st[g][kvs][r], scale, -m_i[g]));
                    hq[r] = (bf16_t)pf;
                    ps += (float)hq[r];
                }
                u[kvs][0] = pack2(hq[0], hq[1]);
                u[kvs][1] = pack2(hq[2], hq[3]);
            }
            ps += __shfl_xor(ps, 16);
            ps += __shfl_xor(ps, 32);
            l_i[g] += ps;

            // exchange D-layout P -> B-fragment layout:
            // need elem e of pb[kk] = P[l15][32kk + 8quad + e]
            int srcA = (quad & 1) * 32 + l15;
            int srcB = srcA + 16;
            for (int kk = 0; kk < 2; ++kk) {
                uint32_t a00 = __shfl((int)u[2 * kk + 0][0], srcA);
                uint32_t a01 = __shfl((int)u[2 * kk + 0][1], srcA);
                uint32_t a10 = __shfl((int)u[2 * kk + 1][0], srcA);
                uint32_t a11 = __shfl((int)u[2 * kk + 1][1], srcA);
                uint32_t b00 = __shfl((int)u[2 * kk + 0][0], srcB);
                uint32_t b01 = __shfl((int)u[2 * kk + 0][1], srcB);
                uint32_t b10 = __shfl((int)u[2 * kk + 1][0], srcB);
                uint32_t b11 = __shfl((int)u[2 * kk + 1][1], srcB);
                union { uint32_t w[4]; bf16x8 v; } cc;
                cc.w[0] = hi2 ? a10 : a00;
                cc.w[1] = hi2 ? a11 : a01;
                cc.w[2] = hi2 ? b10 : b00;
                cc.w[3] = hi2 ? b11 : b01;
                pb[g][kk] = cc.v;
            }
        }

        // PV swapped: each Vt read feeds both groups
        __builtin_amdgcn_s_setprio(1);
        for (int j = 0; j < 8; ++j)
            for (int kk = 0; kk < 2; ++kk) {
                int row = j * 16 + l15;
                int off = (row * 128 + kk * 64 + quad * 16) ^ swz;
                bf16x8 av = *(const bf16x8*)(vt_raw + off);
                ot[0][j] = MFMA16(av, pb[0][kk], ot[0][j]);
                ot[1][j] = MFMA16(av, pb[1][kk], ot[1][j]);
            }
        __builtin_amdgcn_s_setprio(0);

        // One barrier per tile.
        __syncthreads();
    }

    // epilogue: 1/l is lane-local; regs r are contiguous d -> 8B stores
    for (int g = 0; g < 2; ++g) {
        float linv = 1.0f / l_i[g];
        size_t row = (size_t)b * S + q0 + wave * 32 + g * 16 + l15;
        for (int j = 0; j < 8; ++j) {
            union { bf16_t hh[4]; uint2 uu; } o;
            for (int r = 0; r < 4; ++r) o.hh[r] = (bf16_t)(ot[g][j][r] * linv);
            *(uint2*)&Ctx[row * D + h * Dh + j * 16 + quad * 4] = o.uu;
        }
    }
}

// ---------------------------------------------------------------------------
extern "C" void kernel_launch(void* const* d_in, const int* in_sizes, int n_in,
                              void* d_out, int out_size, void* d_ws, size_t ws_size,
                              hipStream_t stream)
{
    const float* x  = (const float*)d_in[0];
    const float* wq = (const float*)d_in[1];
    const float* bq = (const float*)d_in[2];
    const float* wk = (const float*)d_in[3];
    const float* bk = (const float*)d_in[4];
    const float* wv = (const float*)d_in[5];
    const float* bv = (const float*)d_in[6];
    const float* wo = (const float*)d_in[7];
    const float* bo = (const float*)d_in[8];
    float* out = (float*)d_out;

    const int B = 4, S = 2048, D = 2048, H = 16, Dh = 128;
    const int M = B * S;
    const size_t elems  = (size_t)M * D;   // 16,777,216
    const size_t welems = (size_t)D * D;   //  4,194,304

    // ws (bf16): Q | K | V(->Ctx) = 100.7 MiB.
    bf16_t* Qw  = (bf16_t*)d_ws;
    bf16_t* Kw  = Qw + elems;
    bf16_t* Vw  = Kw + elems;
    bf16_t* Ctx = Vw;
    bf16_t* wob = Qw;            // reuse Q region after flash_attn

    // d_out hosts transient bf16 data, dead before the final GEMM writes it.
    // wqb|wkb|wvb are contiguous -> they form the stacked [6144,2048] QKV
    // weight for the merged GEMM.
    bf16_t* outb = (bf16_t*)d_out;
    bf16_t* xb   = outb;
    bf16_t* wqb  = outb + elems;
    bf16_t* wkb  = wqb + welems;
    bf16_t* wvb  = wkb + welems;
    bf16_t* Vtw  = outb;

    cvt_f32_bf16<<<2048, 256, 0, stream>>>(x,  xb,  (int)(elems / 8));
    cvt_f32_bf16<<<2048, 256, 0, stream>>>(wq, wqb, (int)(welems / 8));
    cvt_f32_bf16<<<2048, 256, 0, stream>>>(wk, wkb, (int)(welems / 8));
    cvt_f32_bf16<<<2048, 256, 0, stream>>>(wv, wvb, (int)(welems / 8));

    // Merged QKV projection: one dispatch, grid 64x48 = 4 exact 768-waves.
    dim3 gQKV(M / 128, (3 * D) / 128);
    gemm_qkv<<<gQKV, 256, 0, stream>>>(xb, wqb, bq, bk, bv, Qw, Kw, Vw, M, D);

    size_t nrope = (size_t)M * H * 64;
    rope_kernel<<<(int)(nrope / 256), 256, 0, stream>>>(Qw, Kw);

    dim3 gT(S / 64, Dh / 64, B * H);
    transpose_v<<<gT, 256, 0, stream>>>(Vw, Vtw);

    dim3 gA(S / 128, B * H);
    flash_attn<<<gA, 256, 0, stream>>>(Qw, Kw, Vtw, Ctx);

    cvt_f32_bf16<<<2048, 256, 0, stream>>>(wo, wob, (int)(welems / 8));
    dim3 gGemm(M / 128, D / 128);
    gemm_bt_lds<float><<<gGemm, 256, 0, stream>>>(Ctx, wob, bo, out, M, D, D);
}